// Round 2
// baseline (454.443 us; speedup 1.0000x reference)
//
#include <hip/hip_runtime.h>

typedef unsigned int u32;
typedef unsigned short u16;
typedef __bf16 bf16x8 __attribute__((ext_vector_type(8)));
typedef float f32x16 __attribute__((ext_vector_type(16)));

#define HDIM 128
#define FIN  256
#define NCLS 40
#define NL   4

__device__ __forceinline__ u16 f2b(float f){
  union { __bf16 h; u16 s; } u; u.h = (__bf16)f; return u.s;
}
__device__ __forceinline__ u32 pk(float a, float b){
  union { __bf16 h[2]; u32 w; } u; u.h[0] = (__bf16)a; u.h[1] = (__bf16)b; return u.w;
}
__device__ __forceinline__ float ubf(u32 hbits){
  union { u32 w; float f; } u; u.w = hbits << 16; return u.f;
}

// ---------------- prep: deg/coef + bf16 weights ----------------

__global__ void deg_kernel(const int* __restrict__ ei, float* __restrict__ deg, int E){
  int e = (blockIdx.x * 256 + threadIdx.x) * 4;
  if(e + 3 < E){
    int4 v = *(const int4*)(ei + e);
    atomicAdd(&deg[v.x], 1.0f); atomicAdd(&deg[v.y], 1.0f);
    atomicAdd(&deg[v.z], 1.0f); atomicAdd(&deg[v.w], 1.0f);
  } else {
    for(; e < E; e++) atomicAdd(&deg[ei[e]], 1.0f);
  }
}

__device__ __forceinline__ float dinv(float d){ return d > 0.f ? rsqrtf(d) : 0.f; }

__global__ void coef_kernel(const int* __restrict__ ei, const float* __restrict__ deg,
                            float* __restrict__ coef, int E){
  int e = (blockIdx.x * 256 + threadIdx.x) * 4;
  if(e + 3 < E){
    int4 r = *(const int4*)(ei + e);
    int4 c = *(const int4*)(ei + E + e);
    atomicAdd(&coef[c.x], dinv(deg[r.x]) * dinv(deg[c.x]));
    atomicAdd(&coef[c.y], dinv(deg[r.y]) * dinv(deg[c.y]));
    atomicAdd(&coef[c.z], dinv(deg[r.z]) * dinv(deg[c.z]));
    atomicAdd(&coef[c.w], dinv(deg[r.w]) * dinv(deg[c.w]));
  } else {
    for(; e < E; e++){
      int r = ei[e], c = ei[E + e];
      atomicAdd(&coef[c], dinv(deg[r]) * dinv(deg[c]));
    }
  }
}

// blocks 0..511: encW convert; 512..1023: W_eff rows; 1024..1151: decW (padded to 64 rows)
__global__ void prep_kernel(const float* __restrict__ encW, const float* __restrict__ Wraw,
                            const float* __restrict__ decW,
                            u16* __restrict__ encB, u16* __restrict__ weffB, u16* __restrict__ decB){
  int b = blockIdx.x, t = threadIdx.x;
  if(b < 512){
    int i = b * 64 + t;                     // 32768 elems
    encB[i] = f2b(encW[i]);
  } else if(b < 1024){
    int idx = b - 512;
    int l = idx >> 7, i = idx & 127;
    const float* Wr = Wraw + (size_t)l * HDIM * (HDIM + 2);
    float w0a, w0b, s = 0.f;
    { int j = t;
      float v = (i < j) ? Wr[i*(HDIM+2)+j] : ((j < i) ? Wr[j*(HDIM+2)+i] : 0.f);
      w0a = v; s += fabsf(v); }
    { int j = t + 64;
      float v = (i < j) ? Wr[i*(HDIM+2)+j] : ((j < i) ? Wr[j*(HDIM+2)+i] : 0.f);
      w0b = v; s += fabsf(v); }
    #pragma unroll
    for(int d = 1; d < 64; d <<= 1) s += __shfl_xor(s, d, 64);
    float diag = Wr[i*(HDIM+2)+HDIM] * s + Wr[i*(HDIM+2)+HDIM+1];
    u16* o = weffB + (size_t)l * HDIM * HDIM + i * HDIM;
    o[t]      = f2b((t == i)      ? diag : w0a);
    o[t + 64] = f2b((t + 64 == i) ? diag : w0b);
  } else {
    int idx = b - 1024;                     // 0..127 -> 8192 elems (64x128)
    int i = idx * 64 + t;
    int c = i >> 7, k = i & 127;
    decB[i] = f2b((c < NCLS) ? decW[c * HDIM + k] : 0.f);
  }
}

// ---------------- fused per-node pipeline (no LDS, no barriers) ----------------

// Rebuild MFMA B-fragment (col=lane&31 node, k=(lane>>5)*8+j feature) from packed-bf16 h words.
// packed word m = features (2m, 2m+1) at acc layout: col=lane&31, feat=(r&3)+8*(r>>2)+4*(lane>>5).
__device__ __forceinline__ bf16x8 buildBp(const u32* hw, int s, int hi){
  u32 P0 = hw[4*s+0];
  u32 P1 = hw[4*s+1];
  u32 P2 = hw[4*s+2];
  u32 P3 = hw[4*s+3];
  u32 S0 = hi ? P0 : P2;
  u32 S1 = hi ? P1 : P3;
  u32 R0 = __shfl_xor(S0, 32, 64);
  u32 R1 = __shfl_xor(S1, 32, 64);
  union { u32 w[4]; bf16x8 b; } u;
  u.w[0] = hi ? R0 : P0;
  u.w[1] = hi ? R1 : P1;
  u.w[2] = hi ? P2 : R0;
  u.w[3] = hi ? P3 : R1;
  return u.b;
}

__global__ void __launch_bounds__(256, 3)
mega_kernel(const float* __restrict__ x, const float* __restrict__ enc_b,
            const float* __restrict__ W_b, const float* __restrict__ ext_w,
            const float* __restrict__ beta, const float* __restrict__ dec_b,
            const float* __restrict__ coef,
            const u16* __restrict__ encB, const u16* __restrict__ weffB,
            const u16* __restrict__ decB, float* __restrict__ out, int Nn)
{
  const int tid  = threadIdx.x;
  const int lane = tid & 63;
  const int wv   = tid >> 6;
  const int hi   = lane >> 5;
  const int ln   = lane & 31;
  const int node = blockIdx.x * 128 + wv * 32 + ln;
  const int nd   = node < Nn ? node : (Nn - 1);
  const float cf = coef[nd];

  // ---- encoder: h = enc_W @ x^T  (A = enc_W rows from L1/L2, B = x cols) ----
  f32x16 h[4];
  #pragma unroll
  for(int nt = 0; nt < 4; nt++)
    #pragma unroll
    for(int i = 0; i < 16; i++) h[nt][i] = 0.f;

  const float* xrow = x + (size_t)nd * FIN;
  #pragma unroll
  for(int ks = 0; ks < 16; ks++){
    const float* xp = xrow + ks * 16 + hi * 8;
    float4 a = *(const float4*)xp;
    float4 b = *(const float4*)(xp + 4);
    union { u32 w[4]; bf16x8 v; } B;
    B.w[0] = pk(a.x, a.y); B.w[1] = pk(a.z, a.w);
    B.w[2] = pk(b.x, b.y); B.w[3] = pk(b.z, b.w);
    #pragma unroll
    for(int nt = 0; nt < 4; nt++){
      const bf16x8 A = *(const bf16x8*)(encB + (nt * 32 + ln) * FIN + ks * 16 + hi * 8);
      h[nt] = __builtin_amdgcn_mfma_f32_32x32x16_bf16(A, B.v, h[nt], 0, 0, 0);
    }
  }

  // + enc_b, pack h into bf16 words; snapshot h0
  u32 hp[4][8], h0p[4][8];
  #pragma unroll
  for(int nt = 0; nt < 4; nt++){
    #pragma unroll
    for(int q = 0; q < 4; q++){
      float4 eb = *(const float4*)(enc_b + nt * 32 + 8 * q + 4 * hi);
      h[nt][4*q+0] += eb.x; h[nt][4*q+1] += eb.y;
      h[nt][4*q+2] += eb.z; h[nt][4*q+3] += eb.w;
    }
    #pragma unroll
    for(int m = 0; m < 8; m++){
      u32 w = pk(h[nt][2*m], h[nt][2*m+1]);
      hp[nt][m] = w; h0p[nt][m] = w;
    }
  }

  // ---- 4 layers ----
  #pragma unroll
  for(int l = 0; l < NL; l++){
    const u16* Wl = weffB + (size_t)l * HDIM * HDIM;
    f32x16 acc[4];
    #pragma unroll
    for(int nt = 0; nt < 4; nt++)
      #pragma unroll
      for(int i = 0; i < 16; i++) acc[nt][i] = 0.f;

    #pragma unroll
    for(int ks = 0; ks < 8; ks++){
      bf16x8 B = buildBp(hp[ks >> 1], ks & 1, hi);
      #pragma unroll
      for(int nt = 0; nt < 4; nt++){
        const bf16x8 A = *(const bf16x8*)(Wl + (nt * 32 + ln) * HDIM + ks * 16 + hi * 8);
        acc[nt] = __builtin_amdgcn_mfma_f32_32x32x16_bf16(A, B, acc[nt], 0, 0, 0);
      }
    }

    const float bet = beta[l];
    #pragma unroll
    for(int nt = 0; nt < 4; nt++){
      #pragma unroll
      for(int q = 0; q < 4; q++){
        const int fb = nt * 32 + 8 * q + 4 * hi;
        float4 wb = *(const float4*)(W_b   + l * HDIM + fb);
        float4 ew = *(const float4*)(ext_w + l * HDIM + fb);
        #pragma unroll
        for(int r2 = 0; r2 < 4; r2++){
          const int r = 4 * q + r2;
          float wbv = (r2==0)?wb.x:(r2==1)?wb.y:(r2==2)?wb.z:wb.w;
          float ewv = (r2==0)?ew.x:(r2==1)?ew.y:(r2==2)?ew.z:ew.w;
          u32 w0 = h0p[nt][r >> 1];
          u32 wc = hp[nt][r >> 1];
          float h0v = ubf((r & 1) ? (w0 >> 16) : (w0 & 0xffffu));
          float hv  = ubf((r & 1) ? (wc >> 16) : (wc & 0xffffu));
          float o = cf * (acc[nt][r] + wbv) - hv * ewv - bet * h0v;
          acc[nt][r] = hv + 0.1f * fmaxf(o, 0.f);   // reuse acc as h_new
        }
      }
    }
    #pragma unroll
    for(int nt = 0; nt < 4; nt++)
      #pragma unroll
      for(int m = 0; m < 8; m++)
        hp[nt][m] = pk(acc[nt][2*m], acc[nt][2*m+1]);
  }

  // ---- decoder ----
  f32x16 dac[2];
  #pragma unroll
  for(int nt = 0; nt < 2; nt++)
    #pragma unroll
    for(int i = 0; i < 16; i++) dac[nt][i] = 0.f;

  #pragma unroll
  for(int ks = 0; ks < 8; ks++){
    bf16x8 B = buildBp(hp[ks >> 1], ks & 1, hi);
    #pragma unroll
    for(int nt = 0; nt < 2; nt++){
      const bf16x8 A = *(const bf16x8*)(decB + (nt * 32 + ln) * HDIM + ks * 16 + hi * 8);
      dac[nt] = __builtin_amdgcn_mfma_f32_32x32x16_bf16(A, B, dac[nt], 0, 0, 0);
    }
  }

  if(node < Nn){
    #pragma unroll
    for(int nt = 0; nt < 2; nt++){
      #pragma unroll
      for(int q = 0; q < 4; q++){
        if(nt == 0 || q == 0){                 // classes < 40 only
          const int c0 = nt * 32 + 8 * q + 4 * hi;
          float4 db = *(const float4*)(dec_b + c0);
          float4 v;
          v.x = dac[nt][4*q+0] + db.x;
          v.y = dac[nt][4*q+1] + db.y;
          v.z = dac[nt][4*q+2] + db.z;
          v.w = dac[nt][4*q+3] + db.w;
          *(float4*)(out + (size_t)node * NCLS + c0) = v;
        }
      }
    }
  }
}

extern "C" void kernel_launch(void* const* d_in, const int* in_sizes, int n_in,
                              void* d_out, int out_size, void* d_ws, size_t ws_size,
                              hipStream_t stream){
  (void)n_in; (void)out_size; (void)ws_size;
  const float* x     = (const float*)d_in[0];
  const int*   ei    = (const int*)  d_in[1];
  const float* encW  = (const float*)d_in[2];
  const float* enc_b = (const float*)d_in[3];
  const float* Wraw  = (const float*)d_in[4];
  const float* W_b   = (const float*)d_in[5];
  const float* ext_w = (const float*)d_in[6];
  const float* beta  = (const float*)d_in[7];
  const float* decW  = (const float*)d_in[8];
  const float* dec_b = (const float*)d_in[9];
  float* out = (float*)d_out;
  const int Nn = in_sizes[0] / FIN;
  const int E  = in_sizes[1] / 2;

  char* ws = (char*)d_ws;
  size_t szN = ((size_t)Nn * 4 + 511) & ~(size_t)511;
  float* deg  = (float*)(ws);
  float* coef = (float*)(ws + szN);
  u16* encB  = (u16*)(ws + 2 * szN);
  u16* weffB = (u16*)(ws + 2 * szN + 65536);
  u16* decB  = (u16*)(ws + 2 * szN + 65536 + 131072);

  hipMemsetAsync(ws, 0, 2 * szN, stream);
  prep_kernel<<<1152, 64, 0, stream>>>(encW, Wraw, decW, encB, weffB, decB);
  int egrid = (E / 4 + 255) / 256 + 1;
  deg_kernel <<<egrid, 256, 0, stream>>>(ei, deg, E);
  coef_kernel<<<egrid, 256, 0, stream>>>(ei, deg, coef, E);
  mega_kernel<<<(Nn + 127) / 128, 256, 0, stream>>>(x, enc_b, W_b, ext_w, beta, dec_b,
                                                    coef, encB, weffB, decB, out, Nn);
}

// Round 3
// 343.036 us; speedup vs baseline: 1.3248x; 1.3248x over previous
//
#include <hip/hip_runtime.h>

typedef unsigned int u32;
typedef unsigned short u16;
typedef __bf16 bf16x8 __attribute__((ext_vector_type(8)));
typedef float f32x16 __attribute__((ext_vector_type(16)));

#define HDIM 128
#define FIN  256
#define NCLS 40
#define NL   4

__device__ __forceinline__ u16 f2b(float f){
  union { __bf16 h; u16 s; } u; u.h = (__bf16)f; return u.s;
}
__device__ __forceinline__ u32 pk(float a, float b){
  union { __bf16 h[2]; u32 w; } u; u.h[0] = (__bf16)a; u.h[1] = (__bf16)b; return u.w;
}
__device__ __forceinline__ float ubf(u32 hbits){
  union { u32 w; float f; } u; u.w = hbits << 16; return u.f;
}

// ---------------- prep: deg/coef + bf16 weights ----------------

__global__ void deg_kernel(const int* __restrict__ ei, float* __restrict__ deg, int E){
  int e = (blockIdx.x * 256 + threadIdx.x) * 4;
  if(e + 3 < E){
    int4 v = *(const int4*)(ei + e);
    atomicAdd(&deg[v.x], 1.0f); atomicAdd(&deg[v.y], 1.0f);
    atomicAdd(&deg[v.z], 1.0f); atomicAdd(&deg[v.w], 1.0f);
  } else {
    for(; e < E; e++) atomicAdd(&deg[ei[e]], 1.0f);
  }
}

__device__ __forceinline__ float dinv(float d){ return d > 0.f ? rsqrtf(d) : 0.f; }

__global__ void coef_kernel(const int* __restrict__ ei, const float* __restrict__ deg,
                            float* __restrict__ coef, int E){
  int e = (blockIdx.x * 256 + threadIdx.x) * 4;
  if(e + 3 < E){
    int4 r = *(const int4*)(ei + e);
    int4 c = *(const int4*)(ei + E + e);
    atomicAdd(&coef[c.x], dinv(deg[r.x]) * dinv(deg[c.x]));
    atomicAdd(&coef[c.y], dinv(deg[r.y]) * dinv(deg[c.y]));
    atomicAdd(&coef[c.z], dinv(deg[r.z]) * dinv(deg[c.z]));
    atomicAdd(&coef[c.w], dinv(deg[r.w]) * dinv(deg[c.w]));
  } else {
    for(; e < E; e++){
      int r = ei[e], c = ei[E + e];
      atomicAdd(&coef[c], dinv(deg[r]) * dinv(deg[c]));
    }
  }
}

// blocks 0..511: encW convert; 512..1023: W_eff rows; 1024..1151: decW (padded to 64 rows)
__global__ void prep_kernel(const float* __restrict__ encW, const float* __restrict__ Wraw,
                            const float* __restrict__ decW,
                            u16* __restrict__ encB, u16* __restrict__ weffB, u16* __restrict__ decB){
  int b = blockIdx.x, t = threadIdx.x;
  if(b < 512){
    int i = b * 64 + t;                     // 32768 elems
    encB[i] = f2b(encW[i]);
  } else if(b < 1024){
    int idx = b - 512;
    int l = idx >> 7, i = idx & 127;
    const float* Wr = Wraw + (size_t)l * HDIM * (HDIM + 2);
    float w0a, w0b, s = 0.f;
    { int j = t;
      float v = (i < j) ? Wr[i*(HDIM+2)+j] : ((j < i) ? Wr[j*(HDIM+2)+i] : 0.f);
      w0a = v; s += fabsf(v); }
    { int j = t + 64;
      float v = (i < j) ? Wr[i*(HDIM+2)+j] : ((j < i) ? Wr[j*(HDIM+2)+i] : 0.f);
      w0b = v; s += fabsf(v); }
    #pragma unroll
    for(int d = 1; d < 64; d <<= 1) s += __shfl_xor(s, d, 64);
    float diag = Wr[i*(HDIM+2)+HDIM] * s + Wr[i*(HDIM+2)+HDIM+1];
    u16* o = weffB + (size_t)l * HDIM * HDIM + i * HDIM;
    o[t]      = f2b((t == i)      ? diag : w0a);
    o[t + 64] = f2b((t + 64 == i) ? diag : w0b);
  } else {
    int idx = b - 1024;                     // 0..127 -> 8192 elems (64x128)
    int i = idx * 64 + t;
    int c = i >> 7, k = i & 127;
    decB[i] = f2b((c < NCLS) ? decW[c * HDIM + k] : 0.f);
  }
}

// ---------------- fused per-node pipeline (weights from L1/L2, h0 in LDS) ----------------

// Rebuild MFMA B-fragment (col=lane&31 node, k=(lane>>5)*8+j feature) from packed-bf16 h words.
// packed word m = features (2m, 2m+1) at acc layout: col=lane&31, feat=(r&3)+8*(r>>2)+4*(lane>>5).
__device__ __forceinline__ bf16x8 buildBp(u32 P0, u32 P1, u32 P2, u32 P3, int hi){
  u32 S0 = hi ? P0 : P2;
  u32 S1 = hi ? P1 : P3;
  u32 R0 = __shfl_xor(S0, 32, 64);
  u32 R1 = __shfl_xor(S1, 32, 64);
  union { u32 w[4]; bf16x8 b; } u;
  u.w[0] = hi ? R0 : P0;
  u.w[1] = hi ? R1 : P1;
  u.w[2] = hi ? P2 : R0;
  u.w[3] = hi ? P3 : R1;
  return u.b;
}

__global__ void __launch_bounds__(256, 2)
mega_kernel(const float* __restrict__ x, const float* __restrict__ enc_b,
            const float* __restrict__ W_b, const float* __restrict__ ext_w,
            const float* __restrict__ beta, const float* __restrict__ dec_b,
            const float* __restrict__ coef,
            const u16* __restrict__ encB, const u16* __restrict__ weffB,
            const u16* __restrict__ decB, float* __restrict__ out, int Nn)
{
  // h0 snapshot, packed bf16, thread-private slots (no barriers needed).
  // Layout [word][tid]: 64 consecutive lanes per read row -> conflict-free.
  __shared__ u32 h0s[32][256];

  const int tid  = threadIdx.x;
  const int lane = tid & 63;
  const int wv   = tid >> 6;
  const int hi   = lane >> 5;
  const int ln   = lane & 31;
  const int node = blockIdx.x * 128 + wv * 32 + ln;
  const int nd   = node < Nn ? node : (Nn - 1);
  const float cf = coef[nd];

  // ---- encoder: h = enc_W @ x^T  (A = enc_W rows from L1/L2, B = x cols) ----
  f32x16 h[4];
  #pragma unroll
  for(int nt = 0; nt < 4; nt++)
    #pragma unroll
    for(int i = 0; i < 16; i++) h[nt][i] = 0.f;

  const float* xrow = x + (size_t)nd * FIN;
  #pragma unroll
  for(int ks = 0; ks < 16; ks++){
    const float* xp = xrow + ks * 16 + hi * 8;
    float4 a = *(const float4*)xp;
    float4 b = *(const float4*)(xp + 4);
    union { u32 w[4]; bf16x8 v; } B;
    B.w[0] = pk(a.x, a.y); B.w[1] = pk(a.z, a.w);
    B.w[2] = pk(b.x, b.y); B.w[3] = pk(b.z, b.w);
    #pragma unroll
    for(int nt = 0; nt < 4; nt++){
      const bf16x8 A = *(const bf16x8*)(encB + (nt * 32 + ln) * FIN + ks * 16 + hi * 8);
      h[nt] = __builtin_amdgcn_mfma_f32_32x32x16_bf16(A, B.v, h[nt], 0, 0, 0);
    }
  }

  // + enc_b, pack h into bf16 words (hp in regs); snapshot h0 into LDS
  u32 hp[4][8];
  #pragma unroll
  for(int nt = 0; nt < 4; nt++){
    #pragma unroll
    for(int q = 0; q < 4; q++){
      float4 eb = *(const float4*)(enc_b + nt * 32 + 8 * q + 4 * hi);
      h[nt][4*q+0] += eb.x; h[nt][4*q+1] += eb.y;
      h[nt][4*q+2] += eb.z; h[nt][4*q+3] += eb.w;
    }
    #pragma unroll
    for(int m = 0; m < 8; m++){
      u32 w = pk(h[nt][2*m], h[nt][2*m+1]);
      hp[nt][m] = w;
      h0s[nt * 8 + m][tid] = w;
    }
  }

  // ---- 4 layers ----
  #pragma unroll
  for(int l = 0; l < NL; l++){
    const u16* Wl = weffB + (size_t)l * HDIM * HDIM;
    f32x16 acc[4];
    #pragma unroll
    for(int nt = 0; nt < 4; nt++)
      #pragma unroll
      for(int i = 0; i < 16; i++) acc[nt][i] = 0.f;

    #pragma unroll
    for(int ks = 0; ks < 8; ks++){
      bf16x8 B = buildBp(hp[ks>>1][4*(ks&1)+0], hp[ks>>1][4*(ks&1)+1],
                         hp[ks>>1][4*(ks&1)+2], hp[ks>>1][4*(ks&1)+3], hi);
      #pragma unroll
      for(int nt = 0; nt < 4; nt++){
        const bf16x8 A = *(const bf16x8*)(Wl + (nt * 32 + ln) * HDIM + ks * 16 + hi * 8);
        acc[nt] = __builtin_amdgcn_mfma_f32_32x32x16_bf16(A, B, acc[nt], 0, 0, 0);
      }
    }

    const float bet = beta[l];
    #pragma unroll
    for(int nt = 0; nt < 4; nt++){
      #pragma unroll
      for(int q = 0; q < 4; q++){
        const int fb = nt * 32 + 8 * q + 4 * hi;
        float4 wb = *(const float4*)(W_b   + l * HDIM + fb);
        float4 ew = *(const float4*)(ext_w + l * HDIM + fb);
        #pragma unroll
        for(int r2 = 0; r2 < 4; r2++){
          const int r = 4 * q + r2;
          float wbv = (r2==0)?wb.x:(r2==1)?wb.y:(r2==2)?wb.z:wb.w;
          float ewv = (r2==0)?ew.x:(r2==1)?ew.y:(r2==2)?ew.z:ew.w;
          u32 w0 = h0s[nt * 8 + (r >> 1)][tid];
          u32 wc = hp[nt][r >> 1];
          float h0v = ubf((r & 1) ? (w0 >> 16) : (w0 & 0xffffu));
          float hv  = ubf((r & 1) ? (wc >> 16) : (wc & 0xffffu));
          float o = cf * (acc[nt][r] + wbv) - hv * ewv - bet * h0v;
          acc[nt][r] = hv + 0.1f * fmaxf(o, 0.f);   // reuse acc as h_new
        }
      }
    }
    #pragma unroll
    for(int nt = 0; nt < 4; nt++)
      #pragma unroll
      for(int m = 0; m < 8; m++)
        hp[nt][m] = pk(acc[nt][2*m], acc[nt][2*m+1]);
  }

  // ---- decoder ----
  f32x16 dac[2];
  #pragma unroll
  for(int nt = 0; nt < 2; nt++)
    #pragma unroll
    for(int i = 0; i < 16; i++) dac[nt][i] = 0.f;

  #pragma unroll
  for(int ks = 0; ks < 8; ks++){
    bf16x8 B = buildBp(hp[ks>>1][4*(ks&1)+0], hp[ks>>1][4*(ks&1)+1],
                       hp[ks>>1][4*(ks&1)+2], hp[ks>>1][4*(ks&1)+3], hi);
    #pragma unroll
    for(int nt = 0; nt < 2; nt++){
      const bf16x8 A = *(const bf16x8*)(decB + (nt * 32 + ln) * HDIM + ks * 16 + hi * 8);
      dac[nt] = __builtin_amdgcn_mfma_f32_32x32x16_bf16(A, B, dac[nt], 0, 0, 0);
    }
  }

  if(node < Nn){
    #pragma unroll
    for(int nt = 0; nt < 2; nt++){
      #pragma unroll
      for(int q = 0; q < 4; q++){
        if(nt == 0 || q == 0){                 // classes < 40 only
          const int c0 = nt * 32 + 8 * q + 4 * hi;
          float4 db = *(const float4*)(dec_b + c0);
          float4 v;
          v.x = dac[nt][4*q+0] + db.x;
          v.y = dac[nt][4*q+1] + db.y;
          v.z = dac[nt][4*q+2] + db.z;
          v.w = dac[nt][4*q+3] + db.w;
          *(float4*)(out + (size_t)node * NCLS + c0) = v;
        }
      }
    }
  }
}

extern "C" void kernel_launch(void* const* d_in, const int* in_sizes, int n_in,
                              void* d_out, int out_size, void* d_ws, size_t ws_size,
                              hipStream_t stream){
  (void)n_in; (void)out_size; (void)ws_size;
  const float* x     = (const float*)d_in[0];
  const int*   ei    = (const int*)  d_in[1];
  const float* encW  = (const float*)d_in[2];
  const float* enc_b = (const float*)d_in[3];
  const float* Wraw  = (const float*)d_in[4];
  const float* W_b   = (const float*)d_in[5];
  const float* ext_w = (const float*)d_in[6];
  const float* beta  = (const float*)d_in[7];
  const float* decW  = (const float*)d_in[8];
  const float* dec_b = (const float*)d_in[9];
  float* out = (float*)d_out;
  const int Nn = in_sizes[0] / FIN;
  const int E  = in_sizes[1] / 2;

  char* ws = (char*)d_ws;
  size_t szN = ((size_t)Nn * 4 + 511) & ~(size_t)511;
  float* deg  = (float*)(ws);
  float* coef = (float*)(ws + szN);
  u16* encB  = (u16*)(ws + 2 * szN);
  u16* weffB = (u16*)(ws + 2 * szN + 65536);
  u16* decB  = (u16*)(ws + 2 * szN + 65536 + 131072);

  hipMemsetAsync(ws, 0, 2 * szN, stream);
  prep_kernel<<<1152, 64, 0, stream>>>(encW, Wraw, decW, encB, weffB, decB);
  int egrid = (E / 4 + 255) / 256 + 1;
  deg_kernel <<<egrid, 256, 0, stream>>>(ei, deg, E);
  coef_kernel<<<egrid, 256, 0, stream>>>(ei, deg, coef, E);
  mega_kernel<<<(Nn + 127) / 128, 256, 0, stream>>>(x, enc_b, W_b, ext_w, beta, dec_b,
                                                    coef, encB, weffB, decB, out, Nn);
}

// Round 5
// 334.786 us; speedup vs baseline: 1.3574x; 1.0246x over previous
//
#include <hip/hip_runtime.h>

typedef unsigned int u32;
typedef unsigned short u16;
typedef __bf16 bf16x8 __attribute__((ext_vector_type(8)));
typedef float f32x16 __attribute__((ext_vector_type(16)));
typedef u32 u32x4 __attribute__((ext_vector_type(4)));

#define HDIM 128
#define FIN  256
#define NCLS 40
#define NL   4

__device__ __forceinline__ u16 f2b(float f){
  union { __bf16 h; u16 s; } u; u.h = (__bf16)f; return u.s;
}
__device__ __forceinline__ u32 pk(float a, float b){
  union { __bf16 h[2]; u32 w; } u; u.h[0] = (__bf16)a; u.h[1] = (__bf16)b; return u.w;
}
__device__ __forceinline__ float ubf(u32 hbits){
  union { u32 w; float f; } u; u.w = hbits << 16; return u.f;
}
__device__ __forceinline__ float dinv(float d){ return d > 0.f ? rsqrtf(d) : 0.f; }

// ---------------- prep (EXACT R3 structure, verified) ----------------
// blocks 0..511: encW convert; 512..1023: W_eff rows; 1024..1151: decW (padded to 64 rows)
__global__ void prep_kernel(const float* __restrict__ encW, const float* __restrict__ Wraw,
                            const float* __restrict__ decW,
                            u16* __restrict__ encB, u16* __restrict__ weffB, u16* __restrict__ decB){
  int b = blockIdx.x, t = threadIdx.x;
  if(b < 512){
    int i = b * 64 + t;                     // 32768 elems
    encB[i] = f2b(encW[i]);
  } else if(b < 1024){
    int idx = b - 512;
    int l = idx >> 7, i = idx & 127;
    const float* Wr = Wraw + (size_t)l * HDIM * (HDIM + 2);
    float w0a, w0b, s = 0.f;
    { int j = t;
      float v = (i < j) ? Wr[i*(HDIM+2)+j] : ((j < i) ? Wr[j*(HDIM+2)+i] : 0.f);
      w0a = v; s += fabsf(v); }
    { int j = t + 64;
      float v = (i < j) ? Wr[i*(HDIM+2)+j] : ((j < i) ? Wr[j*(HDIM+2)+i] : 0.f);
      w0b = v; s += fabsf(v); }
    #pragma unroll
    for(int d = 1; d < 64; d <<= 1) s += __shfl_xor(s, d, 64);
    float diag = Wr[i*(HDIM+2)+HDIM] * s + Wr[i*(HDIM+2)+HDIM+1];
    u16* o = weffB + (size_t)l * HDIM * HDIM + i * HDIM;
    o[t]      = f2b((t == i)      ? diag : w0a);
    o[t + 64] = f2b((t + 64 == i) ? diag : w0b);
  } else {
    int idx = b - 1024;                     // 0..127 -> 8192 elems (64x128)
    int i = idx * 64 + t;
    int c = i >> 7, k = i & 127;
    decB[i] = (c < NCLS) ? f2b(decW[c * HDIM + k]) : (u16)0;
  }
}

__global__ void deg_kernel(const int* __restrict__ ei, float* __restrict__ deg, int E){
  long e = ((long)blockIdx.x * 256 + threadIdx.x) * 8;
  if(e + 7 < E){
    int4 v0 = *(const int4*)(ei + e);
    int4 v1 = *(const int4*)(ei + e + 4);
    atomicAdd(&deg[v0.x], 1.0f); atomicAdd(&deg[v0.y], 1.0f);
    atomicAdd(&deg[v0.z], 1.0f); atomicAdd(&deg[v0.w], 1.0f);
    atomicAdd(&deg[v1.x], 1.0f); atomicAdd(&deg[v1.y], 1.0f);
    atomicAdd(&deg[v1.z], 1.0f); atomicAdd(&deg[v1.w], 1.0f);
  } else {
    for(; e < E; e++) atomicAdd(&deg[ei[e]], 1.0f);
  }
}

__global__ void coef_kernel(const int* __restrict__ ei, const float* __restrict__ deg,
                            float* __restrict__ coef, int E){
  long e = ((long)blockIdx.x * 256 + threadIdx.x) * 8;
  if(e + 7 < E){
    int4 r0 = *(const int4*)(ei + e);
    int4 r1 = *(const int4*)(ei + e + 4);
    int4 c0 = *(const int4*)(ei + E + e);
    int4 c1 = *(const int4*)(ei + E + e + 4);
    atomicAdd(&coef[c0.x], dinv(deg[r0.x]) * dinv(deg[c0.x]));
    atomicAdd(&coef[c0.y], dinv(deg[r0.y]) * dinv(deg[c0.y]));
    atomicAdd(&coef[c0.z], dinv(deg[r0.z]) * dinv(deg[c0.z]));
    atomicAdd(&coef[c0.w], dinv(deg[r0.w]) * dinv(deg[c0.w]));
    atomicAdd(&coef[c1.x], dinv(deg[r1.x]) * dinv(deg[c1.x]));
    atomicAdd(&coef[c1.y], dinv(deg[r1.y]) * dinv(deg[c1.y]));
    atomicAdd(&coef[c1.z], dinv(deg[r1.z]) * dinv(deg[c1.z]));
    atomicAdd(&coef[c1.w], dinv(deg[r1.w]) * dinv(deg[c1.w]));
  } else {
    for(; e < E; e++){
      int r = ei[e], c = ei[E + e];
      atomicAdd(&coef[c], dinv(deg[r]) * dinv(deg[c]));
    }
  }
}

__global__ void xconv_kernel(const float* __restrict__ x, u16* __restrict__ xB, long n){
  long i = ((long)blockIdx.x * 256 + threadIdx.x) * 8;
  if(i + 7 < n){
    float4 a = *(const float4*)(x + i);
    float4 c = *(const float4*)(x + i + 4);
    u32x4 w;
    w[0] = pk(a.x, a.y); w[1] = pk(a.z, a.w);
    w[2] = pk(c.x, c.y); w[3] = pk(c.z, c.w);
    *(u32x4*)(xB + i) = w;
  } else {
    for(; i < n; i++) xB[i] = f2b(x[i]);
  }
}

// ---------------- mega: R3 dataflow, two-pass tiles (anti-spill) ----------------

// Rebuild MFMA B-fragment (col=lane&31 node, k=(lane>>5)*8+j feature) from packed-bf16 h words.
__device__ __forceinline__ bf16x8 buildBp(u32 P0, u32 P1, u32 P2, u32 P3, int hi){
  u32 S0 = hi ? P0 : P2;
  u32 S1 = hi ? P1 : P3;
  u32 R0 = __shfl_xor(S0, 32, 64);
  u32 R1 = __shfl_xor(S1, 32, 64);
  union { u32 w[4]; bf16x8 b; } u;
  u.w[0] = hi ? R0 : P0;
  u.w[1] = hi ? R1 : P1;
  u.w[2] = hi ? P2 : R0;
  u.w[3] = hi ? P3 : R1;
  return u.b;
}

template<bool XBF>
__global__ void __launch_bounds__(256, 2)
mega_kernel(const float* __restrict__ x, const u16* __restrict__ xB,
            const float* __restrict__ enc_b,
            const float* __restrict__ W_b, const float* __restrict__ ext_w,
            const float* __restrict__ beta, const float* __restrict__ dec_b,
            const float* __restrict__ coef,
            const u16* __restrict__ encB, const u16* __restrict__ weffB,
            const u16* __restrict__ decB, float* __restrict__ out, int Nn)
{
  // h0 snapshot, packed bf16, thread-private slots (no barriers needed).
  __shared__ u32 h0s[32][256];

  const int tid  = threadIdx.x;
  const int lane = tid & 63;
  const int wv   = tid >> 6;
  const int hi   = lane >> 5;
  const int ln   = lane & 31;
  const int node = blockIdx.x * 128 + wv * 32 + ln;
  const int nd   = node < Nn ? node : (Nn - 1);
  const float cf = coef[nd];

  u32 hp[32];

  // ---- encoder: two passes of 2 row-tiles ----
  #pragma unroll
  for(int P = 0; P < 2; P++){
    f32x16 a0, a1;
    #pragma unroll
    for(int i = 0; i < 16; i++){ a0[i] = 0.f; a1[i] = 0.f; }

    #pragma unroll
    for(int ks = 0; ks < 16; ks++){
      bf16x8 B;
      if(XBF){
        B = *(const bf16x8*)(xB + (size_t)nd * FIN + ks * 16 + hi * 8);
      } else {
        const float* xp = x + (size_t)nd * FIN + ks * 16 + hi * 8;
        float4 a = *(const float4*)xp;
        float4 b = *(const float4*)(xp + 4);
        union { u32 w[4]; bf16x8 v; } Bu;
        Bu.w[0] = pk(a.x, a.y); Bu.w[1] = pk(a.z, a.w);
        Bu.w[2] = pk(b.x, b.y); Bu.w[3] = pk(b.z, b.w);
        B = Bu.v;
      }
      const bf16x8 A0 = *(const bf16x8*)(encB + ((2*P+0) * 32 + ln) * FIN + ks * 16 + hi * 8);
      const bf16x8 A1 = *(const bf16x8*)(encB + ((2*P+1) * 32 + ln) * FIN + ks * 16 + hi * 8);
      a0 = __builtin_amdgcn_mfma_f32_32x32x16_bf16(A0, B, a0, 0, 0, 0);
      a1 = __builtin_amdgcn_mfma_f32_32x32x16_bf16(A1, B, a1, 0, 0, 0);
    }

    #pragma unroll
    for(int t = 0; t < 2; t++){
      const int nt = 2*P + t;
      f32x16& a = t ? a1 : a0;
      #pragma unroll
      for(int q = 0; q < 4; q++){
        float4 eb = *(const float4*)(enc_b + nt * 32 + 8 * q + 4 * hi);
        a[4*q+0] += eb.x; a[4*q+1] += eb.y;
        a[4*q+2] += eb.z; a[4*q+3] += eb.w;
      }
      #pragma unroll
      for(int m = 0; m < 8; m++){
        u32 w = pk(a[2*m], a[2*m+1]);
        hp[nt * 8 + m] = w;
        h0s[nt * 8 + m][tid] = w;
      }
    }
  }

  // ---- 4 layers, each in two passes ----
  #pragma unroll
  for(int l = 0; l < NL; l++){
    const u16* Wl = weffB + (size_t)l * HDIM * HDIM;
    const float bet = beta[l];
    u32 hn[16];

    #pragma unroll
    for(int P = 0; P < 2; P++){
      f32x16 a0, a1;
      #pragma unroll
      for(int i = 0; i < 16; i++){ a0[i] = 0.f; a1[i] = 0.f; }

      #pragma unroll
      for(int ks = 0; ks < 8; ks++){
        const int wbase = (ks >> 1) * 8 + 4 * (ks & 1);
        bf16x8 B = buildBp(hp[wbase+0], hp[wbase+1], hp[wbase+2], hp[wbase+3], hi);
        const bf16x8 A0 = *(const bf16x8*)(Wl + ((2*P+0) * 32 + ln) * HDIM + ks * 16 + hi * 8);
        const bf16x8 A1 = *(const bf16x8*)(Wl + ((2*P+1) * 32 + ln) * HDIM + ks * 16 + hi * 8);
        a0 = __builtin_amdgcn_mfma_f32_32x32x16_bf16(A0, B, a0, 0, 0, 0);
        a1 = __builtin_amdgcn_mfma_f32_32x32x16_bf16(A1, B, a1, 0, 0, 0);
      }

      #pragma unroll
      for(int t = 0; t < 2; t++){
        const int nt = 2*P + t;
        f32x16& a = t ? a1 : a0;
        #pragma unroll
        for(int q = 0; q < 4; q++){
          const int fb = nt * 32 + 8 * q + 4 * hi;
          float4 wb = *(const float4*)(W_b   + l * HDIM + fb);
          float4 ew = *(const float4*)(ext_w + l * HDIM + fb);
          #pragma unroll
          for(int r2 = 0; r2 < 4; r2++){
            const int r = 4 * q + r2;
            float wbv = (r2==0)?wb.x:(r2==1)?wb.y:(r2==2)?wb.z:wb.w;
            float ewv = (r2==0)?ew.x:(r2==1)?ew.y:(r2==2)?ew.z:ew.w;
            u32 w0 = h0s[nt * 8 + (r >> 1)][tid];
            u32 wc = hp[nt * 8 + (r >> 1)];
            float h0v = ubf((r & 1) ? (w0 >> 16) : (w0 & 0xffffu));
            float hv  = ubf((r & 1) ? (wc >> 16) : (wc & 0xffffu));
            float o = cf * (a[r] + wbv) - hv * ewv - bet * h0v;
            a[r] = hv + 0.1f * fmaxf(o, 0.f);
          }
        }
        // pack new h: pass 0 -> hn (hp must stay old for pass 1); pass 1 -> hp directly
        #pragma unroll
        for(int m = 0; m < 8; m++){
          u32 w = pk(a[2*m], a[2*m+1]);
          if(P == 0) hn[nt * 8 + m] = w;
          else       hp[nt * 8 + m] = w;
        }
      }
    }
    #pragma unroll
    for(int m = 0; m < 16; m++) hp[m] = hn[m];
  }

  // ---- decoder (tiles 0,1 cover classes 0..63; only <40 written) ----
  f32x16 d0, d1;
  #pragma unroll
  for(int i = 0; i < 16; i++){ d0[i] = 0.f; d1[i] = 0.f; }

  #pragma unroll
  for(int ks = 0; ks < 8; ks++){
    const int wbase = (ks >> 1) * 8 + 4 * (ks & 1);
    bf16x8 B = buildBp(hp[wbase+0], hp[wbase+1], hp[wbase+2], hp[wbase+3], hi);
    const bf16x8 A0 = *(const bf16x8*)(decB + (0 * 32 + ln) * HDIM + ks * 16 + hi * 8);
    const bf16x8 A1 = *(const bf16x8*)(decB + (1 * 32 + ln) * HDIM + ks * 16 + hi * 8);
    d0 = __builtin_amdgcn_mfma_f32_32x32x16_bf16(A0, B, d0, 0, 0, 0);
    d1 = __builtin_amdgcn_mfma_f32_32x32x16_bf16(A1, B, d1, 0, 0, 0);
  }

  if(node < Nn){
    #pragma unroll
    for(int nt = 0; nt < 2; nt++){
      const f32x16& d = nt ? d1 : d0;
      #pragma unroll
      for(int q = 0; q < 4; q++){
        if(nt == 0 || q == 0){                 // classes < 40 only
          const int c0 = nt * 32 + 8 * q + 4 * hi;
          float4 db = *(const float4*)(dec_b + c0);
          float4 v;
          v.x = d[4*q+0] + db.x;
          v.y = d[4*q+1] + db.y;
          v.z = d[4*q+2] + db.z;
          v.w = d[4*q+3] + db.w;
          *(float4*)(out + (size_t)node * NCLS + c0) = v;
        }
      }
    }
  }
}

extern "C" void kernel_launch(void* const* d_in, const int* in_sizes, int n_in,
                              void* d_out, int out_size, void* d_ws, size_t ws_size,
                              hipStream_t stream){
  (void)n_in; (void)out_size;
  const float* x     = (const float*)d_in[0];
  const int*   ei    = (const int*)  d_in[1];
  const float* encW  = (const float*)d_in[2];
  const float* enc_b = (const float*)d_in[3];
  const float* Wraw  = (const float*)d_in[4];
  const float* W_b   = (const float*)d_in[5];
  const float* ext_w = (const float*)d_in[6];
  const float* beta  = (const float*)d_in[7];
  const float* decW  = (const float*)d_in[8];
  const float* dec_b = (const float*)d_in[9];
  float* out = (float*)d_out;
  const int Nn = in_sizes[0] / FIN;
  const int E  = in_sizes[1] / 2;
  const long xElems = (long)Nn * FIN;

  char* ws = (char*)d_ws;
  size_t szN = ((size_t)Nn * 4 + 511) & ~(size_t)511;
  float* deg  = (float*)(ws);
  float* coef = (float*)(ws + szN);
  u16* encB   = (u16*)(ws + 2 * szN);
  u16* weffB  = (u16*)(ws + 2 * szN + 65536);
  u16* decB   = (u16*)(ws + 2 * szN + 65536 + 131072);
  u16* xB     = (u16*)(ws + 2 * szN + 65536 + 131072 + 16384);
  const size_t need = 2 * szN + 65536 + 131072 + 16384 + (size_t)xElems * 2;
  const bool useXB = ws_size >= need;

  hipMemsetAsync(ws, 0, 2 * szN, stream);
  prep_kernel<<<1152, 64, 0, stream>>>(encW, Wraw, decW, encB, weffB, decB);
  const int egrid = (int)((E / 8 + 255) / 256) + 1;
  deg_kernel <<<egrid, 256, 0, stream>>>(ei, deg, E);
  coef_kernel<<<egrid, 256, 0, stream>>>(ei, deg, coef, E);
  if(useXB){
    xconv_kernel<<<(int)((xElems + 2047) / 2048), 256, 0, stream>>>(x, xB, xElems);
    mega_kernel<true><<<(Nn + 127) / 128, 256, 0, stream>>>(
        x, xB, enc_b, W_b, ext_w, beta, dec_b, coef, encB, weffB, decB, out, Nn);
  } else {
    mega_kernel<false><<<(Nn + 127) / 128, 256, 0, stream>>>(
        x, xB, enc_b, W_b, ext_w, beta, dec_b, coef, encB, weffB, decB, out, Nn);
  }
}

// Round 6
// 329.054 us; speedup vs baseline: 1.3811x; 1.0174x over previous
//
#include <hip/hip_runtime.h>

typedef unsigned int u32;
typedef unsigned short u16;
typedef __bf16 bf16x8 __attribute__((ext_vector_type(8)));
typedef float f32x16 __attribute__((ext_vector_type(16)));

#define HDIM 128
#define FIN  256
#define NCLS 40
#define NL   4

__device__ __forceinline__ u16 f2b(float f){
  union { __bf16 h; u16 s; } u; u.h = (__bf16)f; return u.s;
}
__device__ __forceinline__ u32 pk(float a, float b){
  union { __bf16 h[2]; u32 w; } u; u.h[0] = (__bf16)a; u.h[1] = (__bf16)b; return u.w;
}
__device__ __forceinline__ float ubf(u32 hbits){
  union { u32 w; float f; } u; u.w = hbits << 16; return u.f;
}
__device__ __forceinline__ float dinv(float d){ return d > 0.f ? rsqrtf(d) : 0.f; }

// ---------------- prep (EXACT R3/R5 structure, verified) ----------------
// blocks 0..511: encW convert; 512..1023: W_eff rows; 1024..1151: decW (padded to 64 rows)
__global__ void prep_kernel(const float* __restrict__ encW, const float* __restrict__ Wraw,
                            const float* __restrict__ decW,
                            u16* __restrict__ encB, u16* __restrict__ weffB, u16* __restrict__ decB){
  int b = blockIdx.x, t = threadIdx.x;
  if(b < 512){
    int i = b * 64 + t;                     // 32768 elems
    encB[i] = f2b(encW[i]);
  } else if(b < 1024){
    int idx = b - 512;
    int l = idx >> 7, i = idx & 127;
    const float* Wr = Wraw + (size_t)l * HDIM * (HDIM + 2);
    float w0a, w0b, s = 0.f;
    { int j = t;
      float v = (i < j) ? Wr[i*(HDIM+2)+j] : ((j < i) ? Wr[j*(HDIM+2)+i] : 0.f);
      w0a = v; s += fabsf(v); }
    { int j = t + 64;
      float v = (i < j) ? Wr[i*(HDIM+2)+j] : ((j < i) ? Wr[j*(HDIM+2)+i] : 0.f);
      w0b = v; s += fabsf(v); }
    #pragma unroll
    for(int d = 1; d < 64; d <<= 1) s += __shfl_xor(s, d, 64);
    float diag = Wr[i*(HDIM+2)+HDIM] * s + Wr[i*(HDIM+2)+HDIM+1];
    u16* o = weffB + (size_t)l * HDIM * HDIM + i * HDIM;
    o[t]      = f2b((t == i)      ? diag : w0a);
    o[t + 64] = f2b((t + 64 == i) ? diag : w0b);
  } else {
    int idx = b - 1024;                     // 0..127 -> 8192 elems (64x128)
    int i = idx * 64 + t;
    int c = i >> 7, k = i & 127;
    decB[i] = (c < NCLS) ? f2b(decW[c * HDIM + k]) : (u16)0;
  }
}

__global__ void deg_kernel(const int* __restrict__ ei, float* __restrict__ deg, int E){
  long e = ((long)blockIdx.x * 256 + threadIdx.x) * 8;
  if(e + 7 < E){
    int4 v0 = *(const int4*)(ei + e);
    int4 v1 = *(const int4*)(ei + e + 4);
    atomicAdd(&deg[v0.x], 1.0f); atomicAdd(&deg[v0.y], 1.0f);
    atomicAdd(&deg[v0.z], 1.0f); atomicAdd(&deg[v0.w], 1.0f);
    atomicAdd(&deg[v1.x], 1.0f); atomicAdd(&deg[v1.y], 1.0f);
    atomicAdd(&deg[v1.z], 1.0f); atomicAdd(&deg[v1.w], 1.0f);
  } else {
    for(; e < E; e++) atomicAdd(&deg[ei[e]], 1.0f);
  }
}

__global__ void coef_kernel(const int* __restrict__ ei, const float* __restrict__ deg,
                            float* __restrict__ coef, int E){
  long e = ((long)blockIdx.x * 256 + threadIdx.x) * 8;
  if(e + 7 < E){
    int4 r0 = *(const int4*)(ei + e);
    int4 r1 = *(const int4*)(ei + e + 4);
    int4 c0 = *(const int4*)(ei + E + e);
    int4 c1 = *(const int4*)(ei + E + e + 4);
    atomicAdd(&coef[c0.x], dinv(deg[r0.x]) * dinv(deg[c0.x]));
    atomicAdd(&coef[c0.y], dinv(deg[r0.y]) * dinv(deg[c0.y]));
    atomicAdd(&coef[c0.z], dinv(deg[r0.z]) * dinv(deg[c0.z]));
    atomicAdd(&coef[c0.w], dinv(deg[r0.w]) * dinv(deg[c0.w]));
    atomicAdd(&coef[c1.x], dinv(deg[r1.x]) * dinv(deg[c1.x]));
    atomicAdd(&coef[c1.y], dinv(deg[r1.y]) * dinv(deg[c1.y]));
    atomicAdd(&coef[c1.z], dinv(deg[r1.z]) * dinv(deg[c1.z]));
    atomicAdd(&coef[c1.w], dinv(deg[r1.w]) * dinv(deg[c1.w]));
  } else {
    for(; e < E; e++){
      int r = ei[e], c = ei[E + e];
      atomicAdd(&coef[c], dinv(deg[r]) * dinv(deg[c]));
    }
  }
}

// ---------------- mega: R5 dataflow, two-pass tiles, uncapped registers ----------------

// Rebuild MFMA B-fragment (col=lane&31 node, k=(lane>>5)*8+j feature) from packed-bf16 h words.
__device__ __forceinline__ bf16x8 buildBp(u32 P0, u32 P1, u32 P2, u32 P3, int hi){
  u32 S0 = hi ? P0 : P2;
  u32 S1 = hi ? P1 : P3;
  u32 R0 = __shfl_xor(S0, 32, 64);
  u32 R1 = __shfl_xor(S1, 32, 64);
  union { u32 w[4]; bf16x8 b; } u;
  u.w[0] = hi ? R0 : P0;
  u.w[1] = hi ? R1 : P1;
  u.w[2] = hi ? P2 : R0;
  u.w[3] = hi ? P3 : R1;
  return u.b;
}

__global__ void __launch_bounds__(256, 1)
mega_kernel(const float* __restrict__ x,
            const float* __restrict__ enc_b,
            const float* __restrict__ W_b, const float* __restrict__ ext_w,
            const float* __restrict__ beta, const float* __restrict__ dec_b,
            const float* __restrict__ coef,
            const u16* __restrict__ encB, const u16* __restrict__ weffB,
            const u16* __restrict__ decB, float* __restrict__ out, int Nn)
{
  // h0 snapshot, packed bf16, thread-private slots (no barriers needed).
  __shared__ u32 h0s[32][256];

  const int tid  = threadIdx.x;
  const int lane = tid & 63;
  const int wv   = tid >> 6;
  const int hi   = lane >> 5;
  const int ln   = lane & 31;
  const int node = blockIdx.x * 128 + wv * 32 + ln;
  const int nd   = node < Nn ? node : (Nn - 1);
  const float cf = coef[nd];

  u32 hp[32];

  // ---- encoder: two passes of 2 row-tiles ----
  #pragma unroll
  for(int P = 0; P < 2; P++){
    f32x16 a0, a1;
    #pragma unroll
    for(int i = 0; i < 16; i++){ a0[i] = 0.f; a1[i] = 0.f; }

    #pragma unroll
    for(int ks = 0; ks < 16; ks++){
      const float* xp = x + (size_t)nd * FIN + ks * 16 + hi * 8;
      float4 a = *(const float4*)xp;
      float4 b = *(const float4*)(xp + 4);
      union { u32 w[4]; bf16x8 v; } Bu;
      Bu.w[0] = pk(a.x, a.y); Bu.w[1] = pk(a.z, a.w);
      Bu.w[2] = pk(b.x, b.y); Bu.w[3] = pk(b.z, b.w);
      const bf16x8 A0 = *(const bf16x8*)(encB + ((2*P+0) * 32 + ln) * FIN + ks * 16 + hi * 8);
      const bf16x8 A1 = *(const bf16x8*)(encB + ((2*P+1) * 32 + ln) * FIN + ks * 16 + hi * 8);
      a0 = __builtin_amdgcn_mfma_f32_32x32x16_bf16(A0, Bu.v, a0, 0, 0, 0);
      a1 = __builtin_amdgcn_mfma_f32_32x32x16_bf16(A1, Bu.v, a1, 0, 0, 0);
    }

    #pragma unroll
    for(int t = 0; t < 2; t++){
      const int nt = 2*P + t;
      f32x16& a = t ? a1 : a0;
      #pragma unroll
      for(int q = 0; q < 4; q++){
        float4 eb = *(const float4*)(enc_b + nt * 32 + 8 * q + 4 * hi);
        a[4*q+0] += eb.x; a[4*q+1] += eb.y;
        a[4*q+2] += eb.z; a[4*q+3] += eb.w;
      }
      #pragma unroll
      for(int m = 0; m < 8; m++){
        u32 w = pk(a[2*m], a[2*m+1]);
        hp[nt * 8 + m] = w;
        h0s[nt * 8 + m][tid] = w;
      }
    }
  }

  // ---- 4 layers, each in two passes ----
  #pragma unroll
  for(int l = 0; l < NL; l++){
    const u16* Wl = weffB + (size_t)l * HDIM * HDIM;
    const float bet = beta[l];
    u32 hn[16];

    #pragma unroll
    for(int P = 0; P < 2; P++){
      f32x16 a0, a1;
      #pragma unroll
      for(int i = 0; i < 16; i++){ a0[i] = 0.f; a1[i] = 0.f; }

      #pragma unroll
      for(int ks = 0; ks < 8; ks++){
        const int wbase = (ks >> 1) * 8 + 4 * (ks & 1);
        bf16x8 B = buildBp(hp[wbase+0], hp[wbase+1], hp[wbase+2], hp[wbase+3], hi);
        const bf16x8 A0 = *(const bf16x8*)(Wl + ((2*P+0) * 32 + ln) * HDIM + ks * 16 + hi * 8);
        const bf16x8 A1 = *(const bf16x8*)(Wl + ((2*P+1) * 32 + ln) * HDIM + ks * 16 + hi * 8);
        a0 = __builtin_amdgcn_mfma_f32_32x32x16_bf16(A0, B, a0, 0, 0, 0);
        a1 = __builtin_amdgcn_mfma_f32_32x32x16_bf16(A1, B, a1, 0, 0, 0);
      }

      #pragma unroll
      for(int t = 0; t < 2; t++){
        const int nt = 2*P + t;
        f32x16& a = t ? a1 : a0;
        #pragma unroll
        for(int q = 0; q < 4; q++){
          const int fb = nt * 32 + 8 * q + 4 * hi;
          float4 wb = *(const float4*)(W_b   + l * HDIM + fb);
          float4 ew = *(const float4*)(ext_w + l * HDIM + fb);
          #pragma unroll
          for(int r2 = 0; r2 < 4; r2++){
            const int r = 4 * q + r2;
            float wbv = (r2==0)?wb.x:(r2==1)?wb.y:(r2==2)?wb.z:wb.w;
            float ewv = (r2==0)?ew.x:(r2==1)?ew.y:(r2==2)?ew.z:ew.w;
            u32 w0 = h0s[nt * 8 + (r >> 1)][tid];
            u32 wc = hp[nt * 8 + (r >> 1)];
            float h0v = ubf((r & 1) ? (w0 >> 16) : (w0 & 0xffffu));
            float hv  = ubf((r & 1) ? (wc >> 16) : (wc & 0xffffu));
            float o = cf * (a[r] + wbv) - hv * ewv - bet * h0v;
            a[r] = hv + 0.1f * fmaxf(o, 0.f);
          }
        }
        // pack new h: pass 0 -> hn (hp must stay old for pass 1); pass 1 -> hp directly
        #pragma unroll
        for(int m = 0; m < 8; m++){
          u32 w = pk(a[2*m], a[2*m+1]);
          if(P == 0) hn[nt * 8 + m] = w;
          else       hp[nt * 8 + m] = w;
        }
      }
    }
    #pragma unroll
    for(int m = 0; m < 16; m++) hp[m] = hn[m];
  }

  // ---- decoder (tiles 0,1 cover classes 0..63; only <40 written) ----
  f32x16 d0, d1;
  #pragma unroll
  for(int i = 0; i < 16; i++){ d0[i] = 0.f; d1[i] = 0.f; }

  #pragma unroll
  for(int ks = 0; ks < 8; ks++){
    const int wbase = (ks >> 1) * 8 + 4 * (ks & 1);
    bf16x8 B = buildBp(hp[wbase+0], hp[wbase+1], hp[wbase+2], hp[wbase+3], hi);
    const bf16x8 A0 = *(const bf16x8*)(decB + (0 * 32 + ln) * HDIM + ks * 16 + hi * 8);
    const bf16x8 A1 = *(const bf16x8*)(decB + (1 * 32 + ln) * HDIM + ks * 16 + hi * 8);
    d0 = __builtin_amdgcn_mfma_f32_32x32x16_bf16(A0, B, d0, 0, 0, 0);
    d1 = __builtin_amdgcn_mfma_f32_32x32x16_bf16(A1, B, d1, 0, 0, 0);
  }

  if(node < Nn){
    #pragma unroll
    for(int nt = 0; nt < 2; nt++){
      const f32x16& d = nt ? d1 : d0;
      #pragma unroll
      for(int q = 0; q < 4; q++){
        if(nt == 0 || q == 0){                 // classes < 40 only
          const int c0 = nt * 32 + 8 * q + 4 * hi;
          float4 db = *(const float4*)(dec_b + c0);
          float4 v;
          v.x = d[4*q+0] + db.x;
          v.y = d[4*q+1] + db.y;
          v.z = d[4*q+2] + db.z;
          v.w = d[4*q+3] + db.w;
          *(float4*)(out + (size_t)node * NCLS + c0) = v;
        }
      }
    }
  }
}

extern "C" void kernel_launch(void* const* d_in, const int* in_sizes, int n_in,
                              void* d_out, int out_size, void* d_ws, size_t ws_size,
                              hipStream_t stream){
  (void)n_in; (void)out_size; (void)ws_size;
  const float* x     = (const float*)d_in[0];
  const int*   ei    = (const int*)  d_in[1];
  const float* encW  = (const float*)d_in[2];
  const float* enc_b = (const float*)d_in[3];
  const float* Wraw  = (const float*)d_in[4];
  const float* W_b   = (const float*)d_in[5];
  const float* ext_w = (const float*)d_in[6];
  const float* beta  = (const float*)d_in[7];
  const float* decW  = (const float*)d_in[8];
  const float* dec_b = (const float*)d_in[9];
  float* out = (float*)d_out;
  const int Nn = in_sizes[0] / FIN;
  const int E  = in_sizes[1] / 2;

  char* ws = (char*)d_ws;
  size_t szN = ((size_t)Nn * 4 + 511) & ~(size_t)511;
  float* deg  = (float*)(ws);
  float* coef = (float*)(ws + szN);
  u16* encB   = (u16*)(ws + 2 * szN);
  u16* weffB  = (u16*)(ws + 2 * szN + 65536);
  u16* decB   = (u16*)(ws + 2 * szN + 65536 + 131072);

  hipMemsetAsync(ws, 0, 2 * szN, stream);
  prep_kernel<<<1152, 64, 0, stream>>>(encW, Wraw, decW, encB, weffB, decB);
  const int egrid = (int)((E / 8 + 255) / 256) + 1;
  deg_kernel <<<egrid, 256, 0, stream>>>(ei, deg, E);
  coef_kernel<<<egrid, 256, 0, stream>>>(ei, deg, coef, E);
  mega_kernel<<<(Nn + 127) / 128, 256, 0, stream>>>(
      x, enc_b, W_b, ext_w, beta, dec_b, coef, encB, weffB, decB, out, Nn);
}

// Round 7
// 268.051 us; speedup vs baseline: 1.6954x; 1.2276x over previous
//
#include <hip/hip_runtime.h>

typedef unsigned int u32;
typedef unsigned short u16;
typedef __bf16 bf16x8 __attribute__((ext_vector_type(8)));
typedef float f32x16 __attribute__((ext_vector_type(16)));
typedef u32 u32x4 __attribute__((ext_vector_type(4)));

#define HDIM 128
#define FIN  256
#define NCLS 40
#define NL   4

__device__ __forceinline__ u16 f2b(float f){
  union { __bf16 h; u16 s; } u; u.h = (__bf16)f; return u.s;
}
__device__ __forceinline__ u32 pk(float a, float b){
  union { __bf16 h[2]; u32 w; } u; u.h[0] = (__bf16)a; u.h[1] = (__bf16)b; return u.w;
}
__device__ __forceinline__ float ubf(u32 hbits){
  union { u32 w; float f; } u; u.w = hbits << 16; return u.f;
}
__device__ __forceinline__ float dinv(float d){ return d > 0.f ? rsqrtf(d) : 0.f; }

// Fragment-major index for a 128-row x 128-col weight matrix (layer l block):
// element (row, k) -> ((((tile*8 + ks)*2 + hi)*32 + ln)*8 + j
// tile=row>>5, ln=row&31, ks=k>>4, hi=(k>>3)&1, j=k&7.
__device__ __forceinline__ int fragIdx128(int row, int k){
  return (((((row >> 5) * 8 + (k >> 4)) * 2 + ((k >> 3) & 1)) * 32 + (row & 31)) * 8) + (k & 7);
}

// ---------------- prep: weights -> bf16 fragment-major ----------------
// blocks 0..511: encW; 512..1023: W_eff rows; 1024..1151: decW (row-major, padded 64 rows)
__global__ void prep_kernel(const float* __restrict__ encW, const float* __restrict__ Wraw,
                            const float* __restrict__ decW,
                            u16* __restrict__ encF, u16* __restrict__ weffF, u16* __restrict__ decB){
  int b = blockIdx.x, t = threadIdx.x;
  if(b < 512){
    int i = b * 64 + t;                     // 32768 elems of encW[row][k], row=i>>8, k=i&255
    int row = i >> 8, k = i & 255;
    int chunk = k >> 7, kk = k & 127;
    encF[chunk * 16384 + fragIdx128(row, kk)] = f2b(encW[i]);
  } else if(b < 1024){
    int idx = b - 512;
    int l = idx >> 7, i = idx & 127;
    const float* Wr = Wraw + (size_t)l * HDIM * (HDIM + 2);
    float w0a, w0b, s = 0.f;
    { int j = t;
      float v = (i < j) ? Wr[i*(HDIM+2)+j] : ((j < i) ? Wr[j*(HDIM+2)+i] : 0.f);
      w0a = v; s += fabsf(v); }
    { int j = t + 64;
      float v = (i < j) ? Wr[i*(HDIM+2)+j] : ((j < i) ? Wr[j*(HDIM+2)+i] : 0.f);
      w0b = v; s += fabsf(v); }
    #pragma unroll
    for(int d = 1; d < 64; d <<= 1) s += __shfl_xor(s, d, 64);
    float diag = Wr[i*(HDIM+2)+HDIM] * s + Wr[i*(HDIM+2)+HDIM+1];
    u16* o = weffF + (size_t)l * 16384;
    o[fragIdx128(i, t)]      = f2b((t == i)      ? diag : w0a);
    o[fragIdx128(i, t + 64)] = f2b((t + 64 == i) ? diag : w0b);
  } else {
    int idx = b - 1024;                     // 0..127 -> 8192 elems (64x128), row-major
    int i = idx * 64 + t;
    int c = i >> 7, k = i & 127;
    decB[i] = (c < NCLS) ? f2b(decW[c * HDIM + k]) : (u16)0;
  }
}

__global__ void deg_kernel(const int* __restrict__ ei, float* __restrict__ deg, int E){
  long e = ((long)blockIdx.x * 256 + threadIdx.x) * 8;
  if(e + 7 < E){
    int4 v0 = *(const int4*)(ei + e);
    int4 v1 = *(const int4*)(ei + e + 4);
    atomicAdd(&deg[v0.x], 1.0f); atomicAdd(&deg[v0.y], 1.0f);
    atomicAdd(&deg[v0.z], 1.0f); atomicAdd(&deg[v0.w], 1.0f);
    atomicAdd(&deg[v1.x], 1.0f); atomicAdd(&deg[v1.y], 1.0f);
    atomicAdd(&deg[v1.z], 1.0f); atomicAdd(&deg[v1.w], 1.0f);
  } else {
    for(; e < E; e++) atomicAdd(&deg[ei[e]], 1.0f);
  }
}

__global__ void coef_kernel(const int* __restrict__ ei, const float* __restrict__ deg,
                            float* __restrict__ coef, int E){
  long e = ((long)blockIdx.x * 256 + threadIdx.x) * 8;
  if(e + 7 < E){
    int4 r0 = *(const int4*)(ei + e);
    int4 r1 = *(const int4*)(ei + e + 4);
    int4 c0 = *(const int4*)(ei + E + e);
    int4 c1 = *(const int4*)(ei + E + e + 4);
    atomicAdd(&coef[c0.x], dinv(deg[r0.x]) * dinv(deg[c0.x]));
    atomicAdd(&coef[c0.y], dinv(deg[r0.y]) * dinv(deg[c0.y]));
    atomicAdd(&coef[c0.z], dinv(deg[r0.z]) * dinv(deg[c0.z]));
    atomicAdd(&coef[c0.w], dinv(deg[r0.w]) * dinv(deg[c0.w]));
    atomicAdd(&coef[c1.x], dinv(deg[r1.x]) * dinv(deg[c1.x]));
    atomicAdd(&coef[c1.y], dinv(deg[r1.y]) * dinv(deg[c1.y]));
    atomicAdd(&coef[c1.z], dinv(deg[r1.z]) * dinv(deg[c1.z]));
    atomicAdd(&coef[c1.w], dinv(deg[r1.w]) * dinv(deg[c1.w]));
  } else {
    for(; e < E; e++){
      int r = ei[e], c = ei[E + e];
      atomicAdd(&coef[c], dinv(deg[r]) * dinv(deg[c]));
    }
  }
}

// ---------------- mega: R5 per-wave dataflow, weights via LDS staging ----------------

__device__ __forceinline__ bf16x8 buildBp(u32 P0, u32 P1, u32 P2, u32 P3, int hi){
  u32 S0 = hi ? P0 : P2;
  u32 S1 = hi ? P1 : P3;
  u32 R0 = __shfl_xor(S0, 32, 64);
  u32 R1 = __shfl_xor(S1, 32, 64);
  union { u32 w[4]; bf16x8 b; } u;
  u.w[0] = hi ? R0 : P0;
  u.w[1] = hi ? R1 : P1;
  u.w[2] = hi ? P2 : R0;
  u.w[3] = hi ? P3 : R1;
  return u.b;
}

__device__ __forceinline__ void stage32k(u16* __restrict__ lds, const u16* __restrict__ src, int tid){
  const u32x4* s = (const u32x4*)src;
  u32x4* d = (u32x4*)lds;
  #pragma unroll
  for(int i = 0; i < 8; i++) d[tid + i * 256] = s[tid + i * 256];
}

__global__ void __launch_bounds__(256, 1)
mega_kernel(const float* __restrict__ x,
            const float* __restrict__ enc_b,
            const float* __restrict__ W_b, const float* __restrict__ ext_w,
            const float* __restrict__ beta, const float* __restrict__ dec_b,
            const float* __restrict__ coef,
            const u16* __restrict__ encF, const u16* __restrict__ weffF,
            const u16* __restrict__ decB, float* __restrict__ out, int Nn)
{
  __shared__ u16 lw[16384];        // 32 KB: one enc chunk / one layer, fragment-major
  __shared__ u32 h0s[32][256];     // 32 KB: h0 snapshot, thread-private slots

  const int tid  = threadIdx.x;
  const int lane = tid & 63;
  const int wv   = tid >> 6;
  const int hi   = lane >> 5;
  const int ln   = lane & 31;
  const int node = blockIdx.x * 128 + wv * 32 + ln;
  const int nd   = node < Nn ? node : (Nn - 1);
  const float cf = coef[nd];

  u32 hp[32];

  // ---- encoder: 2 staged chunks of K, all 4 row-tiles accumulated ----
  {
    f32x16 acc[4];
    #pragma unroll
    for(int nt = 0; nt < 4; nt++)
      #pragma unroll
      for(int i = 0; i < 16; i++) acc[nt][i] = 0.f;

    for(int chunk = 0; chunk < 2; chunk++){
      __syncthreads();
      stage32k(lw, encF + chunk * 16384, tid);
      __syncthreads();

      #pragma unroll
      for(int ksl = 0; ksl < 8; ksl++){
        const float* xp = x + (size_t)nd * FIN + chunk * 128 + ksl * 16 + hi * 8;
        float4 va = *(const float4*)xp;
        float4 vb = *(const float4*)(xp + 4);
        union { u32 w[4]; bf16x8 v; } Bu;
        Bu.w[0] = pk(va.x, va.y); Bu.w[1] = pk(va.z, va.w);
        Bu.w[2] = pk(vb.x, vb.y); Bu.w[3] = pk(vb.z, vb.w);
        #pragma unroll
        for(int nt = 0; nt < 4; nt++){
          const bf16x8 A = *(const bf16x8*)(lw + ((((nt * 8 + ksl) * 2 + hi) * 32 + ln) * 8));
          acc[nt] = __builtin_amdgcn_mfma_f32_32x32x16_bf16(A, Bu.v, acc[nt], 0, 0, 0);
        }
      }
    }

    // + enc_b, pack; snapshot h0 into LDS
    #pragma unroll
    for(int nt = 0; nt < 4; nt++){
      #pragma unroll
      for(int q = 0; q < 4; q++){
        float4 eb = *(const float4*)(enc_b + nt * 32 + 8 * q + 4 * hi);
        acc[nt][4*q+0] += eb.x; acc[nt][4*q+1] += eb.y;
        acc[nt][4*q+2] += eb.z; acc[nt][4*q+3] += eb.w;
      }
      #pragma unroll
      for(int m = 0; m < 8; m++){
        u32 w = pk(acc[nt][2*m], acc[nt][2*m+1]);
        hp[nt * 8 + m] = w;
        h0s[nt * 8 + m][tid] = w;
      }
    }
  }

  // ---- 4 layers: stage layer weights, two-pass tiles ----
  for(int l = 0; l < NL; l++){
    __syncthreads();                       // all ds-reads of lw from prev phase done
    stage32k(lw, weffF + l * 16384, tid);
    __syncthreads();

    const float bet = beta[l];
    u32 hn[16];

    #pragma unroll
    for(int P = 0; P < 2; P++){
      f32x16 a0, a1;
      #pragma unroll
      for(int i = 0; i < 16; i++){ a0[i] = 0.f; a1[i] = 0.f; }

      #pragma unroll
      for(int ks = 0; ks < 8; ks++){
        const int wbase = (ks >> 1) * 8 + 4 * (ks & 1);
        bf16x8 B = buildBp(hp[wbase+0], hp[wbase+1], hp[wbase+2], hp[wbase+3], hi);
        const bf16x8 A0 = *(const bf16x8*)(lw + (((((2*P+0) * 8 + ks) * 2 + hi) * 32 + ln) * 8));
        const bf16x8 A1 = *(const bf16x8*)(lw + (((((2*P+1) * 8 + ks) * 2 + hi) * 32 + ln) * 8));
        a0 = __builtin_amdgcn_mfma_f32_32x32x16_bf16(A0, B, a0, 0, 0, 0);
        a1 = __builtin_amdgcn_mfma_f32_32x32x16_bf16(A1, B, a1, 0, 0, 0);
      }

      #pragma unroll
      for(int t = 0; t < 2; t++){
        const int nt = 2*P + t;
        f32x16& a = t ? a1 : a0;
        #pragma unroll
        for(int q = 0; q < 4; q++){
          const int fb = nt * 32 + 8 * q + 4 * hi;
          float4 wb = *(const float4*)(W_b   + l * HDIM + fb);
          float4 ew = *(const float4*)(ext_w + l * HDIM + fb);
          #pragma unroll
          for(int r2 = 0; r2 < 4; r2++){
            const int r = 4 * q + r2;
            float wbv = (r2==0)?wb.x:(r2==1)?wb.y:(r2==2)?wb.z:wb.w;
            float ewv = (r2==0)?ew.x:(r2==1)?ew.y:(r2==2)?ew.z:ew.w;
            u32 w0 = h0s[nt * 8 + (r >> 1)][tid];
            u32 wc = hp[nt * 8 + (r >> 1)];
            float h0v = ubf((r & 1) ? (w0 >> 16) : (w0 & 0xffffu));
            float hv  = ubf((r & 1) ? (wc >> 16) : (wc & 0xffffu));
            float o = cf * (a[r] + wbv) - hv * ewv - bet * h0v;
            a[r] = hv + 0.1f * fmaxf(o, 0.f);
          }
        }
        #pragma unroll
        for(int m = 0; m < 8; m++){
          u32 w = pk(a[2*m], a[2*m+1]);
          if(P == 0) hn[nt * 8 + m] = w;
          else       hp[nt * 8 + m] = w;
        }
      }
    }
    #pragma unroll
    for(int m = 0; m < 16; m++) hp[m] = hn[m];
  }

  // ---- decoder: direct from L2 (16 KB, row-major, verified path) ----
  f32x16 d0, d1;
  #pragma unroll
  for(int i = 0; i < 16; i++){ d0[i] = 0.f; d1[i] = 0.f; }

  #pragma unroll
  for(int ks = 0; ks < 8; ks++){
    const int wbase = (ks >> 1) * 8 + 4 * (ks & 1);
    bf16x8 B = buildBp(hp[wbase+0], hp[wbase+1], hp[wbase+2], hp[wbase+3], hi);
    const bf16x8 A0 = *(const bf16x8*)(decB + (0 * 32 + ln) * HDIM + ks * 16 + hi * 8);
    const bf16x8 A1 = *(const bf16x8*)(decB + (1 * 32 + ln) * HDIM + ks * 16 + hi * 8);
    d0 = __builtin_amdgcn_mfma_f32_32x32x16_bf16(A0, B, d0, 0, 0, 0);
    d1 = __builtin_amdgcn_mfma_f32_32x32x16_bf16(A1, B, d1, 0, 0, 0);
  }

  if(node < Nn){
    #pragma unroll
    for(int nt = 0; nt < 2; nt++){
      const f32x16& d = nt ? d1 : d0;
      #pragma unroll
      for(int q = 0; q < 4; q++){
        if(nt == 0 || q == 0){                 // classes < 40 only
          const int c0 = nt * 32 + 8 * q + 4 * hi;
          float4 db = *(const float4*)(dec_b + c0);
          float4 v;
          v.x = d[4*q+0] + db.x;
          v.y = d[4*q+1] + db.y;
          v.z = d[4*q+2] + db.z;
          v.w = d[4*q+3] + db.w;
          *(float4*)(out + (size_t)node * NCLS + c0) = v;
        }
      }
    }
  }
}

extern "C" void kernel_launch(void* const* d_in, const int* in_sizes, int n_in,
                              void* d_out, int out_size, void* d_ws, size_t ws_size,
                              hipStream_t stream){
  (void)n_in; (void)out_size; (void)ws_size;
  const float* x     = (const float*)d_in[0];
  const int*   ei    = (const int*)  d_in[1];
  const float* encW  = (const float*)d_in[2];
  const float* enc_b = (const float*)d_in[3];
  const float* Wraw  = (const float*)d_in[4];
  const float* W_b   = (const float*)d_in[5];
  const float* ext_w = (const float*)d_in[6];
  const float* beta  = (const float*)d_in[7];
  const float* decW  = (const float*)d_in[8];
  const float* dec_b = (const float*)d_in[9];
  float* out = (float*)d_out;
  const int Nn = in_sizes[0] / FIN;
  const int E  = in_sizes[1] / 2;

  char* ws = (char*)d_ws;
  size_t szN = ((size_t)Nn * 4 + 511) & ~(size_t)511;
  float* deg  = (float*)(ws);
  float* coef = (float*)(ws + szN);
  u16* encF   = (u16*)(ws + 2 * szN);
  u16* weffF  = (u16*)(ws + 2 * szN + 65536);
  u16* decB   = (u16*)(ws + 2 * szN + 65536 + 131072);

  hipMemsetAsync(ws, 0, 2 * szN, stream);
  prep_kernel<<<1152, 64, 0, stream>>>(encW, Wraw, decW, encF, weffF, decB);
  const int egrid = (int)((E / 8 + 255) / 256) + 1;
  deg_kernel <<<egrid, 256, 0, stream>>>(ei, deg, E);
  coef_kernel<<<egrid, 256, 0, stream>>>(ei, deg, coef, E);
  mega_kernel<<<(Nn + 127) / 128, 256, 0, stream>>>(
      x, enc_b, W_b, ext_w, beta, dec_b, coef, encF, weffF, decB, out, Nn);
}